// Round 7
// baseline (858.761 us; speedup 1.0000x reference)
//
#include <hip/hip_runtime.h>

// ============================================================================
// DIAGNOSTIC ROUND: kernels are R4's (best-known structure), each body wrapped
// in an idempotent x4 repetition loop. Purpose: decompose dur_us into
// OH (harness fill + reset memsets + launch) vs G (gemm) vs R (recur).
//   dur_new = OH + 4G + 4R ;  R4: 445 = OH + G + R  =>  G+R = (dur_new-445)/3.
// If 4G (resp. 4R) > ~165us the dispatch enters the rocprof top-5 with its
// own counters. Outputs are bit-identical to R4 (reps rewrite same values).
// ============================================================================

#define T_DIM 256
#define B_DIM 2048
#define D_IN_DIM 128
#define NQ 8
#define ROWS_PER_BLK 64
#define XSTRIDE 129   // X tile pad: read bank = (lane + k) % 32 -> 2-way, free
#define TSTRIDE 33    // transpose tile pad: 2-way, free
#define GREP 4        // gemm repetitions (diagnostic)
#define RREP 4        // recur repetitions (diagnostic)

__global__ __launch_bounds__(256) void qlstm_gemm(
    const float* __restrict__ X,   // chunk base, [rows][128]
    const float* __restrict__ Wf, const float* __restrict__ Wi,
    const float* __restrict__ Wg, const float* __restrict__ Wo,
    const float* __restrict__ bf, const float* __restrict__ bi,
    const float* __restrict__ bg, const float* __restrict__ bo,
    const float* __restrict__ thf, const float* __restrict__ thi,
    const float* __restrict__ thg, const float* __restrict__ tho,
    float4* __restrict__ Z)        // [rows][8] float4
{
    __shared__ float xs[ROWS_PER_BLK * XSTRIDE];   // 33 KB, reused for transpose
    __shared__ float wsh[4 * D_IN_DIM * NQ];       // 16 KB: [gate][k][q]

    const int t = (int)threadIdx.x;
    const int r0 = (int)blockIdx.x * ROWS_PER_BLK;

    const int wid  = __builtin_amdgcn_readfirstlane(t >> 6);  // wave id = gate
    const int lane = t & 63;                                   // row in tile

    const float* W  = (wid == 0) ? Wf  : (wid == 1) ? Wi  : (wid == 2) ? Wg  : Wo;
    const float* BB = (wid == 0) ? bf  : (wid == 1) ? bi  : (wid == 2) ? bg  : bo;
    const float* TH = (wid == 0) ? thf : (wid == 1) ? thi : (wid == 2) ? thg : tho;

    // Stage this wave's gate weights once: [k][q] -> wsh[wid*1024 + k*8 + q].
    {
        const float4* Wg4 = (const float4*)W;            // 256 float4
        float4* wd = (float4*)&wsh[wid * (D_IN_DIM * NQ)];
#pragma unroll
        for (int j = 0; j < 4; j++) wd[j * 64 + lane] = Wg4[j * 64 + lane];
    }

    const float4* Xg = (const float4*)(X + (size_t)r0 * D_IN_DIM);

    for (int rep = 0; rep < GREP; ++rep) {
        __syncthreads();   // xs reused across reps (and covers wsh on rep 0)

        // Stage X tile: 64 rows x 128 floats = 2048 float4, 8/thread, coalesced.
#pragma unroll
        for (int i = 0; i < 8; i++) {
            int L = t + i * 256;
            float4 v = Xg[L];
            int row = L >> 5;          // 32 float4 per row
            int k4  = L & 31;
            float* d = &xs[row * XSTRIDE + k4 * 4];
            d[0] = v.x; d[1] = v.y; d[2] = v.z; d[3] = v.w;
        }
        __syncthreads();

        float acc[NQ];
#pragma unroll
        for (int q = 0; q < NQ; q++) acc[q] = BB[q] + TH[q];

        const float*  xrow = &xs[lane * XSTRIDE];
        const float4* wk   = (const float4*)&wsh[wid * (D_IN_DIM * NQ)];
#pragma unroll 4
        for (int k = 0; k < D_IN_DIM; k++) {
            float xk = xrow[k];
            float4 wa = wk[2 * k];       // w[k][0..3], all lanes same addr (bcast)
            float4 wb = wk[2 * k + 1];   // w[k][4..7]
            acc[0] += xk * wa.x; acc[1] += xk * wa.y; acc[2] += xk * wa.z; acc[3] += xk * wa.w;
            acc[4] += xk * wb.x; acc[5] += xk * wb.y; acc[6] += xk * wb.z; acc[7] += xk * wb.w;
        }

        __syncthreads();
        float* tile = xs;   // [64][TSTRIDE], elem (r, q*4+gate)
#pragma unroll
        for (int q = 0; q < NQ; q++)
            tile[lane * TSTRIDE + q * 4 + wid] = acc[q];
        __syncthreads();

        float4* Zblk = Z + (size_t)r0 * NQ;
#pragma unroll
        for (int i = 0; i < 2; i++) {
            int F = t + i * 256;          // float4 index: r = F>>3, q = F&7
            int r = F >> 3, q = F & 7;
            const float* s = &tile[r * TSTRIDE + q * 4];
            Zblk[F] = make_float4(s[0], s[1], s[2], s[3]);
        }
    }
}

// ---------------------------------------------------------------------------
#define INV_2PI 0.15915494309189535f
#define L2E     1.4426950408889634f

__device__ __forceinline__ float hw_cos(float x) {
    return __builtin_amdgcn_cosf(x * INV_2PI);        // v_cos takes revolutions
}
__device__ __forceinline__ float hw_tanh(float x) {
    return 1.0f - 2.0f * __builtin_amdgcn_rcpf(__builtin_amdgcn_exp2f((2.0f * L2E) * x) + 1.0f);
}

// g(u) ~= tanh(t)/t with u = t^2, fitted on t in [0,1]; max |tanh err| ~2e-4.
#define POLY_G(u) \
    fmaf((u), fmaf((u), fmaf((u), -0.027717f, 0.120472f), -0.331065f), 0.999904f)

#define BCAST8(x, J) \
    __int_as_float(__builtin_amdgcn_ds_swizzle(__float_as_int(x), ((J) << 5) | 0x18))

#define LSTM_STEP_R(zv, hdst) { \
    float h0 = BCAST8(h, 0), h1 = BCAST8(h, 1), h2 = BCAST8(h, 2), h3 = BCAST8(h, 3); \
    float h4 = BCAST8(h, 4), h5 = BCAST8(h, 5), h6 = BCAST8(h, 6), h7 = BCAST8(h, 7); \
    float f0 = fmaf(h0, whf[0], (zv).x), f1 = fmaf(h1, whf[1], 0.0f); \
    float i0 = fmaf(h0, whi[0], (zv).y), i1 = fmaf(h1, whi[1], 0.0f); \
    float g0 = fmaf(h0, whg[0], (zv).z), g1 = fmaf(h1, whg[1], 0.0f); \
    float o0 = fmaf(h0, who[0], (zv).w), o1 = fmaf(h1, who[1], 0.0f); \
    f0 = fmaf(h2, whf[2], f0); f1 = fmaf(h3, whf[3], f1); \
    i0 = fmaf(h2, whi[2], i0); i1 = fmaf(h3, whi[3], i1); \
    g0 = fmaf(h2, whg[2], g0); g1 = fmaf(h3, whg[3], g1); \
    o0 = fmaf(h2, who[2], o0); o1 = fmaf(h3, who[3], o1); \
    f0 = fmaf(h4, whf[4], f0); f1 = fmaf(h5, whf[5], f1); \
    i0 = fmaf(h4, whi[4], i0); i1 = fmaf(h5, whi[5], i1); \
    g0 = fmaf(h4, whg[4], g0); g1 = fmaf(h5, whg[5], g1); \
    o0 = fmaf(h4, who[4], o0); o1 = fmaf(h5, who[5], o1); \
    f0 = fmaf(h6, whf[6], f0); f1 = fmaf(h7, whf[7], f1); \
    i0 = fmaf(h6, whi[6], i0); i1 = fmaf(h7, whi[7], i1); \
    g0 = fmaf(h6, whg[6], g0); g1 = fmaf(h7, whg[7], g1); \
    o0 = fmaf(h6, who[6], o0); o1 = fmaf(h7, who[7], o1); \
    float tf = hw_cos(f0 + f1); \
    float ti = hw_cos(i0 + i1); \
    float tg = hw_cos(g0 + g1); \
    float to = hw_cos(o0 + o1); \
    float pf = POLY_G(0.25f * (tf * tf)); \
    float pi_ = POLY_G(0.25f * (ti * ti)); \
    float pg = POLY_G(tg * tg); \
    float po = POLY_G(0.25f * (to * to)); \
    float fg = fmaf(tf * pf, 0.25f, 0.5f); \
    float ig = fmaf(ti * pi_, 0.25f, 0.5f); \
    float gg = tg * pg; \
    float og = fmaf(to * po, 0.25f, 0.5f); \
    c = fmaf(fg, c, ig * gg); \
    h = og * hw_tanh(c); \
    (hdst) = h; }

__global__ __launch_bounds__(64) void qlstm_recur(
    const float4* __restrict__ Z,  // chunk base, [ct][B*NQ] float4
    const float* __restrict__ Wf, const float* __restrict__ Wi,
    const float* __restrict__ Wg, const float* __restrict__ Wo,
    float* __restrict__ out,       // full output base
    float* __restrict__ state,     // [h: B*8][c: B*8]
    int t0, int ct, int first, int last)
{
    const int tid = (int)blockIdx.x * 64 + (int)threadIdx.x;  // 0..16383
    const int q   = tid & 7;

    float whf[8], whi[8], whg[8], who[8];
#pragma unroll
    for (int j = 0; j < 8; j++) {
        whf[j] = Wf[(D_IN_DIM + j) * NQ + q];
        whi[j] = Wi[(D_IN_DIM + j) * NQ + q];
        whg[j] = Wg[(D_IN_DIM + j) * NQ + q];
        who[j] = Wo[(D_IN_DIM + j) * NQ + q];
    }

    float h_init, c_init;
    if (first) { h_init = 0.0f; c_init = 0.0f; }
    else       { h_init = state[tid]; c_init = state[B_DIM * NQ + tid]; }

    const size_t stepsz = (size_t)B_DIM * NQ;   // 16384
    const float4* Zp = Z + tid;

    float h, c;
    float4 bufA[8], bufB[8];
    float houtA[8], houtB[8];

    for (int rep = 0; rep < RREP; ++rep) {
        h = h_init; c = c_init;
        float* og_ptr = out + (size_t)t0 * stepsz + tid;

        // Prologue: fill A with steps 0..7 (ct is a multiple of 16, >= 16).
#pragma unroll
        for (int s = 0; s < 8; s++) bufA[s] = Zp[(size_t)s * stepsz];

        for (int tb = 0; tb < ct; tb += 16) {
            // Issue loads for steps tb+8..tb+15 into B.
#pragma unroll
            for (int s = 0; s < 8; s++) bufB[s] = Zp[(size_t)(tb + 8 + s) * stepsz];
            __builtin_amdgcn_sched_barrier(0);   // pin: loads stay issued here
            // Consume A: steps tb..tb+7.
#pragma unroll
            for (int s = 0; s < 8; s++) {
                float4 z = bufA[s];
                LSTM_STEP_R(z, houtA[s])
            }
            // Issue loads for steps tb+16..tb+23 into A (skip on last group).
            if (tb + 16 < ct) {
#pragma unroll
                for (int s = 0; s < 8; s++) bufA[s] = Zp[(size_t)(tb + 16 + s) * stepsz];
            }
            __builtin_amdgcn_sched_barrier(0);
            // Batched stores of A-group outputs.
#pragma unroll
            for (int s = 0; s < 8; s++) og_ptr[(size_t)s * stepsz] = houtA[s];
            // Consume B: steps tb+8..tb+15.
#pragma unroll
            for (int s = 0; s < 8; s++) {
                float4 z = bufB[s];
                LSTM_STEP_R(z, houtB[s])
            }
            // Batched stores of B-group outputs.
#pragma unroll
            for (int s = 0; s < 8; s++) og_ptr[(size_t)(8 + s) * stepsz] = houtB[s];
            og_ptr += (size_t)16 * stepsz;
        }
    }

    if (last) {
        out[(size_t)T_DIM * stepsz + tid] = h;
        out[(size_t)T_DIM * stepsz + stepsz + tid] = c;
    } else {
        state[tid] = h;
        state[B_DIM * NQ + tid] = c;
    }
}

// ---------------------------------------------------------------------------
extern "C" void kernel_launch(void* const* d_in, const int* in_sizes, int n_in,
                              void* d_out, int out_size, void* d_ws, size_t ws_size,
                              hipStream_t stream) {
    const float* X   = (const float*)d_in[0];
    const float* Wf  = (const float*)d_in[1];
    const float* bf  = (const float*)d_in[2];
    const float* Wi  = (const float*)d_in[3];
    const float* bi  = (const float*)d_in[4];
    const float* Wg  = (const float*)d_in[5];
    const float* bg  = (const float*)d_in[6];
    const float* Wo  = (const float*)d_in[7];
    const float* bo  = (const float*)d_in[8];
    const float* thf = (const float*)d_in[9];
    const float* thi = (const float*)d_in[10];
    const float* thg = (const float*)d_in[11];
    const float* tho = (const float*)d_in[12];
    float* out = (float*)d_out;

    const size_t state_bytes = (size_t)2 * B_DIM * NQ * sizeof(float);  // 128 KiB
    float* state = (float*)d_ws;
    float4* Zbuf = (float4*)((char*)d_ws + state_bytes);
    size_t avail = ws_size > state_bytes ? ws_size - state_bytes : 0;
    const size_t z_bytes_per_t = (size_t)B_DIM * NQ * sizeof(float4);   // 256 KiB
    int maxChunkT = (int)(avail / z_bytes_per_t);
    if (maxChunkT > T_DIM) maxChunkT = T_DIM;
    maxChunkT &= ~15;                  // recur requires multiples of 16
    if (maxChunkT < 16) maxChunkT = 16; // ws assumed >= ~4.2 MiB

    int t0 = 0;
    int first = 1;
    while (t0 < T_DIM) {
        int ct = (T_DIM - t0 < maxChunkT) ? (T_DIM - t0) : maxChunkT;
        int rows = ct * B_DIM;
        qlstm_gemm<<<rows / ROWS_PER_BLK, 256, 0, stream>>>(
            X + (size_t)t0 * B_DIM * D_IN_DIM,
            Wf, Wi, Wg, Wo, bf, bi, bg, bo, thf, thi, thg, tho,
            Zbuf);
        int last = (t0 + ct == T_DIM) ? 1 : 0;
        qlstm_recur<<<(B_DIM * NQ) / 64, 64, 0, stream>>>(
            Zbuf, Wf, Wi, Wg, Wo, out, state, t0, ct, first, last);
        t0 += ct;
        first = 0;
    }
}

// Round 8
// 440.141 us; speedup vs baseline: 1.9511x; 1.9511x over previous
//
#include <hip/hip_runtime.h>

#define T_DIM 256
#define B_DIM 2048
#define D_IN_DIM 128
#define NQ 8
#define ROWS_PER_BLK 64
#define XR 136        // bf16 row stride of X tile (128 data + 8 pad): 272 B = 17*16B
#define WR 136        // bf16 row stride of Wt
#define TSTRIDE 33    // f32 transpose tile pad

typedef __attribute__((ext_vector_type(8))) short bf16x8;
typedef __attribute__((ext_vector_type(4))) float f32x4;

__device__ __forceinline__ ushort f2bf(float x) {   // RNE float->bf16 bits
    union { float f; unsigned u; } a; a.f = x;
    unsigned r = a.u + 0x7fff + ((a.u >> 16) & 1);
    return (ushort)(r >> 16);
}

// ---------------------------------------------------------------------------
// Kernel 1: Z[row][q] = float4(f,i,g,o) of x[row].W[:,q] + b[q] + th[q]
// THIS ROUND: MFMA. R7 diagnostic showed G~108us with warm-cache reps no
// faster than cold -> instruction/LDS-issue bound (1024 VALU FMA + 384
// ds_read per wave per tile), HBM floor ~60us. MFMA removes ~90% of the
// instructions: per wave 8x mfma_f32_16x16x32_bf16 + 12 b128 frag reads.
// X tile cast to bf16 on staging; W pre-transposed to Wt[c=q*4+gate][k] bf16
// so B-frags are contiguous; fp32 accumulate; bias+theta added in epilogue.
// LDS 26.3 KB -> 6 blocks/CU.
// Fragment maps (guide-verified for 16x16x32 bf16): lane holds
//   A[lane&15][kt*32 + (lane>>4)*8 + j],  B[same k][lane&15],
//   D[(lane>>4)*4 + reg][lane&15].
// ---------------------------------------------------------------------------
__global__ __launch_bounds__(256) void qlstm_gemm(
    const float* __restrict__ X,   // chunk base, [rows][128]
    const float* __restrict__ Wf, const float* __restrict__ Wi,
    const float* __restrict__ Wg, const float* __restrict__ Wo,
    const float* __restrict__ bf, const float* __restrict__ bi,
    const float* __restrict__ bg, const float* __restrict__ bo,
    const float* __restrict__ thf, const float* __restrict__ thi,
    const float* __restrict__ thg, const float* __restrict__ tho,
    float4* __restrict__ Z)        // [rows][8] float4
{
    __shared__ ushort xlds[ROWS_PER_BLK * XR];   // 17.4 KB; overlaid by f32 tile [64][33]
    __shared__ ushort wt[32 * WR];               // 8.7 KB: Wt[c][k] bf16, c = q*4+gate
    __shared__ float bsh[32];                    // bias[c] = b[q]+th[q]

    const int t = (int)threadIdx.x;
    const int r0 = (int)blockIdx.x * ROWS_PER_BLK;
    const int wid  = __builtin_amdgcn_readfirstlane(t >> 6);  // wave id = gate
    const int lane = t & 63;

    // --- stage Wt (each wave handles its gate's 128x8 block) ---
    {
        const float* W = (wid == 0) ? Wf : (wid == 1) ? Wi : (wid == 2) ? Wg : Wo;
        const float4* Wg4 = (const float4*)W;            // 256 float4, [k][q] rows
#pragma unroll
        for (int j = 0; j < 4; j++) {
            int i = j * 64 + lane;          // float4 index: k = i>>1, q0 = (i&1)*4
            float4 v = Wg4[i];
            int k = i >> 1, q0 = (i & 1) * 4;
            wt[((q0 + 0) * 4 + wid) * WR + k] = f2bf(v.x);
            wt[((q0 + 1) * 4 + wid) * WR + k] = f2bf(v.y);
            wt[((q0 + 2) * 4 + wid) * WR + k] = f2bf(v.z);
            wt[((q0 + 3) * 4 + wid) * WR + k] = f2bf(v.w);
        }
    }
    if (t < 32) {
        int gate = t & 3, q = t >> 2;
        const float* bb = (gate == 0) ? bf  : (gate == 1) ? bi  : (gate == 2) ? bg  : bo;
        const float* th = (gate == 0) ? thf : (gate == 1) ? thi : (gate == 2) ? thg : tho;
        bsh[t] = bb[q] + th[q];
    }

    // --- stage X tile as bf16: 64 rows x 128, coalesced float4 reads ---
    const float4* Xg = (const float4*)(X + (size_t)r0 * D_IN_DIM);
#pragma unroll
    for (int i = 0; i < 8; i++) {
        int L = t + i * 256;
        float4 v = Xg[L];
        int row = L >> 5;          // 32 float4 per row
        int k4  = (L & 31) * 4;
        ushort4 p;
        p.x = f2bf(v.x); p.y = f2bf(v.y); p.z = f2bf(v.z); p.w = f2bf(v.w);
        *(ushort4*)&xlds[row * XR + k4] = p;   // 8B ds_write
    }
    __syncthreads();

    // --- MFMA: wave wid covers rows band..band+15, all 32 cols ---
    const int band = wid * 16;
    const int arow = band + (lane & 15);
    const int koff = (lane >> 4) * 8;
    f32x4 d0 = {0.f, 0.f, 0.f, 0.f};
    f32x4 d1 = {0.f, 0.f, 0.f, 0.f};
#pragma unroll
    for (int kt = 0; kt < 4; kt++) {
        bf16x8 a  = *(const bf16x8*)&xlds[arow * XR + kt * 32 + koff];
        bf16x8 b0 = *(const bf16x8*)&wt[(lane & 15) * WR + kt * 32 + koff];
        bf16x8 b1 = *(const bf16x8*)&wt[(16 + (lane & 15)) * WR + kt * 32 + koff];
        d0 = __builtin_amdgcn_mfma_f32_16x16x32_bf16(a, b0, d0, 0, 0, 0);
        d1 = __builtin_amdgcn_mfma_f32_16x16x32_bf16(a, b1, d1, 0, 0, 0);
    }
    __syncthreads();   // all frag reads done; xlds can be overlaid

    // --- transpose through LDS for coalesced float4 Z stores ---
    float* tile = (float*)xlds;   // [64][TSTRIDE] f32 = 8.4 KB overlay
    {
        int drow = band + (lane >> 4) * 4;
        int c = lane & 15;
#pragma unroll
        for (int r = 0; r < 4; r++) {
            tile[(drow + r) * TSTRIDE + c]      = d0[r];
            tile[(drow + r) * TSTRIDE + 16 + c] = d1[r];
        }
    }
    __syncthreads();

    float4* Zblk = Z + (size_t)r0 * NQ;
#pragma unroll
    for (int i = 0; i < 2; i++) {
        int F = t + i * 256;          // float4 index: r = F>>3, q = F&7
        int r = F >> 3, q = F & 7;
        const float* s = &tile[r * TSTRIDE + q * 4];
        Zblk[F] = make_float4(s[0] + bsh[q * 4 + 0], s[1] + bsh[q * 4 + 1],
                              s[2] + bsh[q * 4 + 2], s[3] + bsh[q * 4 + 3]);
    }
}

// ---------------------------------------------------------------------------
// Kernel 2: sequential recurrence. 256 blocks x 64 thr. UNCHANGED from the
// round-4 passing version (R ~ 30us, not the bottleneck).
// ---------------------------------------------------------------------------
#define INV_2PI 0.15915494309189535f
#define L2E     1.4426950408889634f

__device__ __forceinline__ float hw_cos(float x) {
    return __builtin_amdgcn_cosf(x * INV_2PI);        // v_cos takes revolutions
}
__device__ __forceinline__ float hw_tanh(float x) {
    return 1.0f - 2.0f * __builtin_amdgcn_rcpf(__builtin_amdgcn_exp2f((2.0f * L2E) * x) + 1.0f);
}

// g(u) ~= tanh(t)/t with u = t^2, fitted on t in [0,1]; max |tanh err| ~2e-4.
#define POLY_G(u) \
    fmaf((u), fmaf((u), fmaf((u), -0.027717f, 0.120472f), -0.331065f), 0.999904f)

#define BCAST8(x, J) \
    __int_as_float(__builtin_amdgcn_ds_swizzle(__float_as_int(x), ((J) << 5) | 0x18))

#define LSTM_STEP_R(zv, hdst) { \
    float h0 = BCAST8(h, 0), h1 = BCAST8(h, 1), h2 = BCAST8(h, 2), h3 = BCAST8(h, 3); \
    float h4 = BCAST8(h, 4), h5 = BCAST8(h, 5), h6 = BCAST8(h, 6), h7 = BCAST8(h, 7); \
    float f0 = fmaf(h0, whf[0], (zv).x), f1 = fmaf(h1, whf[1], 0.0f); \
    float i0 = fmaf(h0, whi[0], (zv).y), i1 = fmaf(h1, whi[1], 0.0f); \
    float g0 = fmaf(h0, whg[0], (zv).z), g1 = fmaf(h1, whg[1], 0.0f); \
    float o0 = fmaf(h0, who[0], (zv).w), o1 = fmaf(h1, who[1], 0.0f); \
    f0 = fmaf(h2, whf[2], f0); f1 = fmaf(h3, whf[3], f1); \
    i0 = fmaf(h2, whi[2], i0); i1 = fmaf(h3, whi[3], i1); \
    g0 = fmaf(h2, whg[2], g0); g1 = fmaf(h3, whg[3], g1); \
    o0 = fmaf(h2, who[2], o0); o1 = fmaf(h3, who[3], o1); \
    f0 = fmaf(h4, whf[4], f0); f1 = fmaf(h5, whf[5], f1); \
    i0 = fmaf(h4, whi[4], i0); i1 = fmaf(h5, whi[5], i1); \
    g0 = fmaf(h4, whg[4], g0); g1 = fmaf(h5, whg[5], g1); \
    o0 = fmaf(h4, who[4], o0); o1 = fmaf(h5, who[5], o1); \
    f0 = fmaf(h6, whf[6], f0); f1 = fmaf(h7, whf[7], f1); \
    i0 = fmaf(h6, whi[6], i0); i1 = fmaf(h7, whi[7], i1); \
    g0 = fmaf(h6, whg[6], g0); g1 = fmaf(h7, whg[7], g1); \
    o0 = fmaf(h6, who[6], o0); o1 = fmaf(h7, who[7], o1); \
    float tf = hw_cos(f0 + f1); \
    float ti = hw_cos(i0 + i1); \
    float tg = hw_cos(g0 + g1); \
    float to = hw_cos(o0 + o1); \
    float pf = POLY_G(0.25f * (tf * tf)); \
    float pi_ = POLY_G(0.25f * (ti * ti)); \
    float pg = POLY_G(tg * tg); \
    float po = POLY_G(0.25f * (to * to)); \
    float fg = fmaf(tf * pf, 0.25f, 0.5f); \
    float ig = fmaf(ti * pi_, 0.25f, 0.5f); \
    float gg = tg * pg; \
    float og = fmaf(to * po, 0.25f, 0.5f); \
    c = fmaf(fg, c, ig * gg); \
    h = og * hw_tanh(c); \
    (hdst) = h; }

__global__ __launch_bounds__(64) void qlstm_recur(
    const float4* __restrict__ Z,  // chunk base, [ct][B*NQ] float4
    const float* __restrict__ Wf, const float* __restrict__ Wi,
    const float* __restrict__ Wg, const float* __restrict__ Wo,
    float* __restrict__ out,       // full output base
    float* __restrict__ state,     // [h: B*8][c: B*8]
    int t0, int ct, int first, int last)
{
    const int tid = (int)blockIdx.x * 64 + (int)threadIdx.x;  // 0..16383
    const int q   = tid & 7;

    float whf[8], whi[8], whg[8], who[8];
#pragma unroll
    for (int j = 0; j < 8; j++) {
        whf[j] = Wf[(D_IN_DIM + j) * NQ + q];
        whi[j] = Wi[(D_IN_DIM + j) * NQ + q];
        whg[j] = Wg[(D_IN_DIM + j) * NQ + q];
        who[j] = Wo[(D_IN_DIM + j) * NQ + q];
    }

    float h, c;
    if (first) { h = 0.0f; c = 0.0f; }
    else       { h = state[tid]; c = state[B_DIM * NQ + tid]; }

    const size_t stepsz = (size_t)B_DIM * NQ;   // 16384
    const float4* Zp = Z + tid;
    float* og_ptr = out + (size_t)t0 * stepsz + tid;

    float4 bufA[8], bufB[8];
    float houtA[8], houtB[8];
    // Prologue: fill A with steps 0..7 (ct is a multiple of 16, >= 16).
#pragma unroll
    for (int s = 0; s < 8; s++) bufA[s] = Zp[(size_t)s * stepsz];

    for (int tb = 0; tb < ct; tb += 16) {
        // Issue loads for steps tb+8..tb+15 into B.
#pragma unroll
        for (int s = 0; s < 8; s++) bufB[s] = Zp[(size_t)(tb + 8 + s) * stepsz];
        __builtin_amdgcn_sched_barrier(0);   // pin: loads stay issued here
        // Consume A: steps tb..tb+7 -> dedicated hout registers, NO stores.
#pragma unroll
        for (int s = 0; s < 8; s++) {
            float4 z = bufA[s];
            LSTM_STEP_R(z, houtA[s])
        }
        // Issue loads for steps tb+16..tb+23 into A (skip on last group).
        if (tb + 16 < ct) {
#pragma unroll
            for (int s = 0; s < 8; s++) bufA[s] = Zp[(size_t)(tb + 16 + s) * stepsz];
        }
        __builtin_amdgcn_sched_barrier(0);
        // Batched stores of A-group outputs (registers rewritten >=16 steps later).
#pragma unroll
        for (int s = 0; s < 8; s++) og_ptr[(size_t)s * stepsz] = houtA[s];
        // Consume B: steps tb+8..tb+15.
#pragma unroll
        for (int s = 0; s < 8; s++) {
            float4 z = bufB[s];
            LSTM_STEP_R(z, houtB[s])
        }
        // Batched stores of B-group outputs.
#pragma unroll
        for (int s = 0; s < 8; s++) og_ptr[(size_t)(8 + s) * stepsz] = houtB[s];
        og_ptr += (size_t)16 * stepsz;
    }

    if (last) {
        out[(size_t)T_DIM * stepsz + tid] = h;
        out[(size_t)T_DIM * stepsz + stepsz + tid] = c;
    } else {
        state[tid] = h;
        state[B_DIM * NQ + tid] = c;
    }
}

// ---------------------------------------------------------------------------
extern "C" void kernel_launch(void* const* d_in, const int* in_sizes, int n_in,
                              void* d_out, int out_size, void* d_ws, size_t ws_size,
                              hipStream_t stream) {
    const float* X   = (const float*)d_in[0];
    const float* Wf  = (const float*)d_in[1];
    const float* bf  = (const float*)d_in[2];
    const float* Wi  = (const float*)d_in[3];
    const float* bi  = (const float*)d_in[4];
    const float* Wg  = (const float*)d_in[5];
    const float* bg  = (const float*)d_in[6];
    const float* Wo  = (const float*)d_in[7];
    const float* bo  = (const float*)d_in[8];
    const float* thf = (const float*)d_in[9];
    const float* thi = (const float*)d_in[10];
    const float* thg = (const float*)d_in[11];
    const float* tho = (const float*)d_in[12];
    float* out = (float*)d_out;

    const size_t state_bytes = (size_t)2 * B_DIM * NQ * sizeof(float);  // 128 KiB
    float* state = (float*)d_ws;
    float4* Zbuf = (float4*)((char*)d_ws + state_bytes);
    size_t avail = ws_size > state_bytes ? ws_size - state_bytes : 0;
    const size_t z_bytes_per_t = (size_t)B_DIM * NQ * sizeof(float4);   // 256 KiB
    int maxChunkT = (int)(avail / z_bytes_per_t);
    if (maxChunkT > T_DIM) maxChunkT = T_DIM;
    maxChunkT &= ~15;                  // recur requires multiples of 16
    if (maxChunkT < 16) maxChunkT = 16; // ws assumed >= ~4.2 MiB

    int t0 = 0;
    int first = 1;
    while (t0 < T_DIM) {
        int ct = (T_DIM - t0 < maxChunkT) ? (T_DIM - t0) : maxChunkT;
        int rows = ct * B_DIM;
        qlstm_gemm<<<rows / ROWS_PER_BLK, 256, 0, stream>>>(
            X + (size_t)t0 * B_DIM * D_IN_DIM,
            Wf, Wi, Wg, Wo, bf, bi, bg, bo, thf, thi, thg, tho,
            Zbuf);
        int last = (t0 + ct == T_DIM) ? 1 : 0;
        qlstm_recur<<<(B_DIM * NQ) / 64, 64, 0, stream>>>(
            Zbuf, Wf, Wi, Wg, Wo, out, state, t0, ct, first, last);
        t0 += ct;
        first = 0;
    }
}

// Round 10
// 436.967 us; speedup vs baseline: 1.9653x; 1.0073x over previous
//
#include <hip/hip_runtime.h>

#define T_DIM 256
#define B_DIM 2048
#define D_IN_DIM 128
#define NQ 8
#define ROWS_PER_BLK 64
#define XR 136        // bf16 row stride of X tile (128 data + 8 pad): 272 B = 17*16B
#define WR 136        // bf16 row stride of Wt
#define TSTRIDE 33    // f32 transpose tile pad

typedef __attribute__((ext_vector_type(8))) short bf16x8;
typedef __attribute__((ext_vector_type(4))) float f32x4;
typedef __attribute__((ext_vector_type(2))) __fp16 fp16x2;   // cvt_pkrtz return type

__device__ __forceinline__ ushort f2bf(float x) {   // RNE float->bf16 bits
    union { float f; unsigned u; } a; a.f = x;
    unsigned r = a.u + 0x7fff + ((a.u >> 16) & 1);
    return (ushort)(r >> 16);
}
__device__ __forceinline__ unsigned pkh2(float a, float b) {  // 2xf32 -> packed fp16 (RTZ)
    fp16x2 h = __builtin_amdgcn_cvt_pkrtz(a, b);
    unsigned u; __builtin_memcpy(&u, &h, 4); return u;
}
__device__ __forceinline__ float h2f(ushort s) {
    _Float16 x; __builtin_memcpy(&x, &s, 2); return (float)x;
}

// ---------------------------------------------------------------------------
// Kernel 1: MFMA gemm (R8 structure). THIS ROUND: Z stored as fp16 (uint2 =
// 4 halves f,i,g,o) -- halves Z write traffic (67->34 MB). Everything else
// byte-identical to R8. (R9 was a compile-time typo in the pack typedef.)
// ---------------------------------------------------------------------------
__global__ __launch_bounds__(256) void qlstm_gemm(
    const float* __restrict__ X,   // chunk base, [rows][128]
    const float* __restrict__ Wf, const float* __restrict__ Wi,
    const float* __restrict__ Wg, const float* __restrict__ Wo,
    const float* __restrict__ bf, const float* __restrict__ bi,
    const float* __restrict__ bg, const float* __restrict__ bo,
    const float* __restrict__ thf, const float* __restrict__ thi,
    const float* __restrict__ thg, const float* __restrict__ tho,
    uint2* __restrict__ Z)         // [rows][8] uint2 (4 fp16: f,i,g,o)
{
    __shared__ ushort xlds[ROWS_PER_BLK * XR];   // 17.4 KB; overlaid by f32 tile [64][33]
    __shared__ ushort wt[32 * WR];               // 8.7 KB: Wt[c][k] bf16, c = q*4+gate
    __shared__ float bsh[32];                    // bias[c] = b[q]+th[q]

    const int t = (int)threadIdx.x;
    const int r0 = (int)blockIdx.x * ROWS_PER_BLK;
    const int wid  = __builtin_amdgcn_readfirstlane(t >> 6);  // wave id = gate
    const int lane = t & 63;

    // --- stage Wt (each wave handles its gate's 128x8 block) ---
    {
        const float* W = (wid == 0) ? Wf : (wid == 1) ? Wi : (wid == 2) ? Wg : Wo;
        const float4* Wg4 = (const float4*)W;            // 256 float4, [k][q] rows
#pragma unroll
        for (int j = 0; j < 4; j++) {
            int i = j * 64 + lane;          // float4 index: k = i>>1, q0 = (i&1)*4
            float4 v = Wg4[i];
            int k = i >> 1, q0 = (i & 1) * 4;
            wt[((q0 + 0) * 4 + wid) * WR + k] = f2bf(v.x);
            wt[((q0 + 1) * 4 + wid) * WR + k] = f2bf(v.y);
            wt[((q0 + 2) * 4 + wid) * WR + k] = f2bf(v.z);
            wt[((q0 + 3) * 4 + wid) * WR + k] = f2bf(v.w);
        }
    }
    if (t < 32) {
        int gate = t & 3, q = t >> 2;
        const float* bb = (gate == 0) ? bf  : (gate == 1) ? bi  : (gate == 2) ? bg  : bo;
        const float* th = (gate == 0) ? thf : (gate == 1) ? thi : (gate == 2) ? thg : tho;
        bsh[t] = bb[q] + th[q];
    }

    // --- stage X tile as bf16: 64 rows x 128, coalesced float4 reads ---
    const float4* Xg = (const float4*)(X + (size_t)r0 * D_IN_DIM);
#pragma unroll
    for (int i = 0; i < 8; i++) {
        int L = t + i * 256;
        float4 v = Xg[L];
        int row = L >> 5;          // 32 float4 per row
        int k4  = (L & 31) * 4;
        ushort4 p;
        p.x = f2bf(v.x); p.y = f2bf(v.y); p.z = f2bf(v.z); p.w = f2bf(v.w);
        *(ushort4*)&xlds[row * XR + k4] = p;   // 8B ds_write
    }
    __syncthreads();

    // --- MFMA: wave wid covers rows band..band+15, all 32 cols ---
    const int band = wid * 16;
    const int arow = band + (lane & 15);
    const int koff = (lane >> 4) * 8;
    f32x4 d0 = {0.f, 0.f, 0.f, 0.f};
    f32x4 d1 = {0.f, 0.f, 0.f, 0.f};
#pragma unroll
    for (int kt = 0; kt < 4; kt++) {
        bf16x8 a  = *(const bf16x8*)&xlds[arow * XR + kt * 32 + koff];
        bf16x8 b0 = *(const bf16x8*)&wt[(lane & 15) * WR + kt * 32 + koff];
        bf16x8 b1 = *(const bf16x8*)&wt[(16 + (lane & 15)) * WR + kt * 32 + koff];
        d0 = __builtin_amdgcn_mfma_f32_16x16x32_bf16(a, b0, d0, 0, 0, 0);
        d1 = __builtin_amdgcn_mfma_f32_16x16x32_bf16(a, b1, d1, 0, 0, 0);
    }
    __syncthreads();   // all frag reads done; xlds can be overlaid

    // --- transpose through LDS for coalesced Z stores ---
    float* tile = (float*)xlds;   // [64][TSTRIDE] f32 = 8.4 KB overlay
    {
        int drow = band + (lane >> 4) * 4;
        int c = lane & 15;
#pragma unroll
        for (int r = 0; r < 4; r++) {
            tile[(drow + r) * TSTRIDE + c]      = d0[r];
            tile[(drow + r) * TSTRIDE + 16 + c] = d1[r];
        }
    }
    __syncthreads();

    uint2* Zblk = Z + (size_t)r0 * NQ;
#pragma unroll
    for (int i = 0; i < 2; i++) {
        int F = t + i * 256;          // uint2 index: r = F>>3, q = F&7
        int r = F >> 3, q = F & 7;
        const float* s = &tile[r * TSTRIDE + q * 4];
        uint2 w;
        w.x = pkh2(s[0] + bsh[q * 4 + 0], s[1] + bsh[q * 4 + 1]);
        w.y = pkh2(s[2] + bsh[q * 4 + 2], s[3] + bsh[q * 4 + 3]);
        Zblk[F] = w;
    }
}

// ---------------------------------------------------------------------------
// Kernel 2: sequential recurrence. 256 blocks x 64 thr. Same structure as the
// R4 passing version; only the Z loads are now fp16 uint2 (8 B/step) with
// 4x v_cvt_f32_f16 unpack per step.
// ---------------------------------------------------------------------------
#define INV_2PI 0.15915494309189535f
#define L2E     1.4426950408889634f

__device__ __forceinline__ float hw_cos(float x) {
    return __builtin_amdgcn_cosf(x * INV_2PI);        // v_cos takes revolutions
}
__device__ __forceinline__ float hw_tanh(float x) {
    return 1.0f - 2.0f * __builtin_amdgcn_rcpf(__builtin_amdgcn_exp2f((2.0f * L2E) * x) + 1.0f);
}

// g(u) ~= tanh(t)/t with u = t^2, fitted on t in [0,1]; max |tanh err| ~2e-4.
#define POLY_G(u) \
    fmaf((u), fmaf((u), fmaf((u), -0.027717f, 0.120472f), -0.331065f), 0.999904f)

#define BCAST8(x, J) \
    __int_as_float(__builtin_amdgcn_ds_swizzle(__float_as_int(x), ((J) << 5) | 0x18))

#define LSTM_STEP_R(zv, hdst) { \
    float h0 = BCAST8(h, 0), h1 = BCAST8(h, 1), h2 = BCAST8(h, 2), h3 = BCAST8(h, 3); \
    float h4 = BCAST8(h, 4), h5 = BCAST8(h, 5), h6 = BCAST8(h, 6), h7 = BCAST8(h, 7); \
    float f0 = fmaf(h0, whf[0], (zv).x), f1 = fmaf(h1, whf[1], 0.0f); \
    float i0 = fmaf(h0, whi[0], (zv).y), i1 = fmaf(h1, whi[1], 0.0f); \
    float g0 = fmaf(h0, whg[0], (zv).z), g1 = fmaf(h1, whg[1], 0.0f); \
    float o0 = fmaf(h0, who[0], (zv).w), o1 = fmaf(h1, who[1], 0.0f); \
    f0 = fmaf(h2, whf[2], f0); f1 = fmaf(h3, whf[3], f1); \
    i0 = fmaf(h2, whi[2], i0); i1 = fmaf(h3, whi[3], i1); \
    g0 = fmaf(h2, whg[2], g0); g1 = fmaf(h3, whg[3], g1); \
    o0 = fmaf(h2, who[2], o0); o1 = fmaf(h3, who[3], o1); \
    f0 = fmaf(h4, whf[4], f0); f1 = fmaf(h5, whf[5], f1); \
    i0 = fmaf(h4, whi[4], i0); i1 = fmaf(h5, whi[5], i1); \
    g0 = fmaf(h4, whg[4], g0); g1 = fmaf(h5, whg[5], g1); \
    o0 = fmaf(h4, who[4], o0); o1 = fmaf(h5, who[5], o1); \
    f0 = fmaf(h6, whf[6], f0); f1 = fmaf(h7, whf[7], f1); \
    i0 = fmaf(h6, whi[6], i0); i1 = fmaf(h7, whi[7], i1); \
    g0 = fmaf(h6, whg[6], g0); g1 = fmaf(h7, whg[7], g1); \
    o0 = fmaf(h6, who[6], o0); o1 = fmaf(h7, who[7], o1); \
    float tf = hw_cos(f0 + f1); \
    float ti = hw_cos(i0 + i1); \
    float tg = hw_cos(g0 + g1); \
    float to = hw_cos(o0 + o1); \
    float pf = POLY_G(0.25f * (tf * tf)); \
    float pi_ = POLY_G(0.25f * (ti * ti)); \
    float pg = POLY_G(tg * tg); \
    float po = POLY_G(0.25f * (to * to)); \
    float fg = fmaf(tf * pf, 0.25f, 0.5f); \
    float ig = fmaf(ti * pi_, 0.25f, 0.5f); \
    float gg = tg * pg; \
    float og = fmaf(to * po, 0.25f, 0.5f); \
    c = fmaf(fg, c, ig * gg); \
    h = og * hw_tanh(c); \
    (hdst) = h; }

__device__ __forceinline__ float4 unpkz(uint2 u) {
    float4 z;
    z.x = h2f((ushort)(u.x & 0xffff)); z.y = h2f((ushort)(u.x >> 16));
    z.z = h2f((ushort)(u.y & 0xffff)); z.w = h2f((ushort)(u.y >> 16));
    return z;
}

__global__ __launch_bounds__(64) void qlstm_recur(
    const uint2* __restrict__ Z,   // chunk base, [ct][B*NQ] uint2 (4 fp16)
    const float* __restrict__ Wf, const float* __restrict__ Wi,
    const float* __restrict__ Wg, const float* __restrict__ Wo,
    float* __restrict__ out,       // full output base
    float* __restrict__ state,     // [h: B*8][c: B*8]
    int t0, int ct, int first, int last)
{
    const int tid = (int)blockIdx.x * 64 + (int)threadIdx.x;  // 0..16383
    const int q   = tid & 7;

    float whf[8], whi[8], whg[8], who[8];
#pragma unroll
    for (int j = 0; j < 8; j++) {
        whf[j] = Wf[(D_IN_DIM + j) * NQ + q];
        whi[j] = Wi[(D_IN_DIM + j) * NQ + q];
        whg[j] = Wg[(D_IN_DIM + j) * NQ + q];
        who[j] = Wo[(D_IN_DIM + j) * NQ + q];
    }

    float h, c;
    if (first) { h = 0.0f; c = 0.0f; }
    else       { h = state[tid]; c = state[B_DIM * NQ + tid]; }

    const size_t stepsz = (size_t)B_DIM * NQ;   // 16384
    const uint2* Zp = Z + tid;
    float* og_ptr = out + (size_t)t0 * stepsz + tid;

    uint2 bufA[8], bufB[8];
    float houtA[8], houtB[8];
    // Prologue: fill A with steps 0..7 (ct is a multiple of 16, >= 16).
#pragma unroll
    for (int s = 0; s < 8; s++) bufA[s] = Zp[(size_t)s * stepsz];

    for (int tb = 0; tb < ct; tb += 16) {
        // Issue loads for steps tb+8..tb+15 into B.
#pragma unroll
        for (int s = 0; s < 8; s++) bufB[s] = Zp[(size_t)(tb + 8 + s) * stepsz];
        __builtin_amdgcn_sched_barrier(0);   // pin: loads stay issued here
        // Consume A: steps tb..tb+7 -> dedicated hout registers, NO stores.
#pragma unroll
        for (int s = 0; s < 8; s++) {
            float4 z = unpkz(bufA[s]);
            LSTM_STEP_R(z, houtA[s])
        }
        // Issue loads for steps tb+16..tb+23 into A (skip on last group).
        if (tb + 16 < ct) {
#pragma unroll
            for (int s = 0; s < 8; s++) bufA[s] = Zp[(size_t)(tb + 16 + s) * stepsz];
        }
        __builtin_amdgcn_sched_barrier(0);
        // Batched stores of A-group outputs (registers rewritten >=16 steps later).
#pragma unroll
        for (int s = 0; s < 8; s++) og_ptr[(size_t)s * stepsz] = houtA[s];
        // Consume B: steps tb+8..tb+15.
#pragma unroll
        for (int s = 0; s < 8; s++) {
            float4 z = unpkz(bufB[s]);
            LSTM_STEP_R(z, houtB[s])
        }
        // Batched stores of B-group outputs.
#pragma unroll
        for (int s = 0; s < 8; s++) og_ptr[(size_t)(8 + s) * stepsz] = houtB[s];
        og_ptr += (size_t)16 * stepsz;
    }

    if (last) {
        out[(size_t)T_DIM * stepsz + tid] = h;
        out[(size_t)T_DIM * stepsz + stepsz + tid] = c;
    } else {
        state[tid] = h;
        state[B_DIM * NQ + tid] = c;
    }
}

// ---------------------------------------------------------------------------
extern "C" void kernel_launch(void* const* d_in, const int* in_sizes, int n_in,
                              void* d_out, int out_size, void* d_ws, size_t ws_size,
                              hipStream_t stream) {
    const float* X   = (const float*)d_in[0];
    const float* Wf  = (const float*)d_in[1];
    const float* bf  = (const float*)d_in[2];
    const float* Wi  = (const float*)d_in[3];
    const float* bi  = (const float*)d_in[4];
    const float* Wg  = (const float*)d_in[5];
    const float* bg  = (const float*)d_in[6];
    const float* Wo  = (const float*)d_in[7];
    const float* bo  = (const float*)d_in[8];
    const float* thf = (const float*)d_in[9];
    const float* thi = (const float*)d_in[10];
    const float* thg = (const float*)d_in[11];
    const float* tho = (const float*)d_in[12];
    float* out = (float*)d_out;

    const size_t state_bytes = (size_t)2 * B_DIM * NQ * sizeof(float);  // 128 KiB
    float* state = (float*)d_ws;
    uint2* Zbuf = (uint2*)((char*)d_ws + state_bytes);
    size_t avail = ws_size > state_bytes ? ws_size - state_bytes : 0;
    const size_t z_bytes_per_t = (size_t)B_DIM * NQ * sizeof(uint2);    // 128 KiB
    int maxChunkT = (int)(avail / z_bytes_per_t);
    if (maxChunkT > T_DIM) maxChunkT = T_DIM;
    maxChunkT &= ~15;                  // recur requires multiples of 16
    if (maxChunkT < 16) maxChunkT = 16; // ws assumed >= ~2.1 MiB

    int t0 = 0;
    int first = 1;
    while (t0 < T_DIM) {
        int ct = (T_DIM - t0 < maxChunkT) ? (T_DIM - t0) : maxChunkT;
        int rows = ct * B_DIM;
        qlstm_gemm<<<rows / ROWS_PER_BLK, 256, 0, stream>>>(
            X + (size_t)t0 * B_DIM * D_IN_DIM,
            Wf, Wi, Wg, Wo, bf, bi, bg, bo, thf, thi, thg, tho,
            Zbuf);
        int last = (t0 + ct == T_DIM) ? 1 : 0;
        qlstm_recur<<<(B_DIM * NQ) / 64, 64, 0, stream>>>(
            Zbuf, Wf, Wi, Wg, Wo, out, state, t0, ct, first, last);
        t0 += ct;
        first = 0;
    }
}